// Round 1
// baseline (1213.060 us; speedup 1.0000x reference)
//
#include <hip/hip_runtime.h>
#include <hip/hip_bf16.h>

#define NN 50000
#define NE 800000

__device__ __forceinline__ float bf2f(unsigned short u) {
  union { unsigned int i; float f; } v; v.i = ((unsigned int)u) << 16; return v.f;
}
__device__ __forceinline__ unsigned short f2bf(float f) {
  union { unsigned int i; float f; } v; v.f = f;
  unsigned int x = v.i;
  return (unsigned short)((x + 0x7FFFu + ((x >> 16) & 1u)) >> 16);
}

// ---- dtype probe: if first 128 bf16-interpretations are all sane, data is bf16 ----
__global__ void k_detect(const unsigned short* __restrict__ xh, int* __restrict__ flag) {
  int t = threadIdx.x;  // 64 threads
  float b0 = bf2f(xh[2 * t]);
  float b1 = bf2f(xh[2 * t + 1]);
  bool ok = (b0 == b0) && (b1 == b1) && fabsf(b0) < 64.f && fabsf(b1) < 64.f;
  unsigned long long m = __ballot(ok);
  if (t == 0) *flag = (m == ~0ull) ? 1 : 0;
}

__global__ void k_cvt(const void* __restrict__ src, float* __restrict__ dst, int n,
                      const int* __restrict__ flag) {
  int i = blockIdx.x * 256 + threadIdx.x;
  if (i >= n) return;
  if (*flag) dst[i] = bf2f(((const unsigned short*)src)[i]);
  else       dst[i] = ((const float*)src)[i];
}

struct SmallPack { const void* src[20]; int off[21]; };

__global__ void k_cvt_small(SmallPack pk, float* __restrict__ dst, int total,
                            const int* __restrict__ flag) {
  int i = blockIdx.x * 256 + threadIdx.x;
  if (i >= total) return;
  int d = 0;
  while (i >= pk.off[d + 1]) d++;
  int local = i - pk.off[d];
  if (*flag) dst[i] = bf2f(((const unsigned short*)pk.src[d])[local]);
  else       dst[i] = ((const float*)pk.src[d])[local];
}

// ---- CSR build ----
__global__ void k_count(const int* __restrict__ dst, int* __restrict__ fill) {
  int e = blockIdx.x * 256 + threadIdx.x;
  if (e < NE) atomicAdd(&fill[dst[e]], 1);
}

__global__ void k_scan1(const int* __restrict__ deg, int* __restrict__ outp, int* __restrict__ csum) {
  __shared__ int s[256];
  int t = threadIdx.x, i = blockIdx.x * 256 + t;
  int v = (i < NN) ? deg[i] : 0;
  s[t] = v; __syncthreads();
  for (int o = 1; o < 256; o <<= 1) {
    int x = (t >= o) ? s[t - o] : 0; __syncthreads();
    s[t] += x; __syncthreads();
  }
  if (i < NN) outp[i] = s[t] - v;          // exclusive within chunk
  if (t == 255) csum[blockIdx.x] = s[255]; // chunk total
}

__global__ void k_scan2(int* __restrict__ csum, int nc) {
  __shared__ int s[256];
  int t = threadIdx.x;
  int v = (t < nc) ? csum[t] : 0;
  s[t] = v; __syncthreads();
  for (int o = 1; o < 256; o <<= 1) {
    int x = (t >= o) ? s[t - o] : 0; __syncthreads();
    s[t] += x; __syncthreads();
  }
  if (t < nc) csum[t] = s[t] - v;          // exclusive chunk offsets
}

__global__ void k_scan3(int* __restrict__ indptr, const int* __restrict__ csum, int* __restrict__ fill) {
  int i = blockIdx.x * 256 + threadIdx.x;
  if (i < NN) { int v = indptr[i] + csum[blockIdx.x]; indptr[i] = v; fill[i] = v; }
  if (i == NN) indptr[NN] = NE;
}

__global__ void k_fill(const int* __restrict__ src, const int* __restrict__ dst,
                       int* __restrict__ fill, int* __restrict__ csr) {
  int e = blockIdx.x * 256 + threadIdx.x;
  if (e < NE) { int p = atomicAdd(&fill[dst[e]], 1); csr[p] = src[e]; }
}

// ---- fp32 tiled GEMM: Z[M][Nc] = A[M][K] * W[K][Nc] ----
__global__ __launch_bounds__(256) void k_gemm(const float* __restrict__ A, const float* __restrict__ W,
                                              float* __restrict__ Z, int M, int K, int Nc) {
  __shared__ alignas(16) float As[32][68];  // [k][m]
  __shared__ alignas(16) float Bs[32][68];  // [k][n]
  int tid = threadIdx.x;
  int tx = tid & 15, ty = tid >> 4;
  int row0 = blockIdx.y * 64, col0 = blockIdx.x * 64;
  float acc[4][4] = {};
  for (int k0 = 0; k0 < K; k0 += 32) {
#pragma unroll
    for (int j = 0; j < 2; j++) {
      int v = tid + 256 * j;
      int arow = v >> 3, aq = v & 7;
      float4 a = make_float4(0.f, 0.f, 0.f, 0.f);
      int grow = row0 + arow;
      if (grow < M) a = *(const float4*)&A[(size_t)grow * K + k0 + aq * 4];
      As[aq * 4 + 0][arow] = a.x; As[aq * 4 + 1][arow] = a.y;
      As[aq * 4 + 2][arow] = a.z; As[aq * 4 + 3][arow] = a.w;
      int brow = v >> 4, bq = v & 15;
      float4 b = make_float4(0.f, 0.f, 0.f, 0.f);
      int gcol = col0 + bq * 4;
      if (gcol < Nc) b = *(const float4*)&W[(size_t)(k0 + brow) * Nc + gcol];
      *(float4*)&Bs[brow][bq * 4] = b;
    }
    __syncthreads();
#pragma unroll
    for (int kk = 0; kk < 32; kk++) {
      float4 a4 = *(const float4*)&As[kk][ty * 4];
      float4 b4 = *(const float4*)&Bs[kk][tx * 4];
      float av[4] = {a4.x, a4.y, a4.z, a4.w};
      float bv[4] = {b4.x, b4.y, b4.z, b4.w};
#pragma unroll
      for (int i = 0; i < 4; i++)
#pragma unroll
        for (int jj = 0; jj < 4; jj++) acc[i][jj] += av[i] * bv[jj];
    }
    __syncthreads();
  }
#pragma unroll
  for (int i = 0; i < 4; i++) {
    int grow = row0 + ty * 4 + i;
    if (grow >= M) continue;
#pragma unroll
    for (int jj = 0; jj < 4; jj++) {
      int gcol = col0 + tx * 4 + jj;
      if (gcol < Nc) Z[(size_t)grow * Nc + gcol] = acc[i][jj];
    }
  }
}

// ---- el/er: wave per (n,h), F=64 ----
__global__ void k_scores(const float* __restrict__ Z, const float* __restrict__ al,
                         const float* __restrict__ ar, float* __restrict__ el,
                         float* __restrict__ er, int H) {
  int g = blockIdx.x * 256 + threadIdx.x;
  int wid = g >> 6, lane = g & 63;
  if (wid >= NN * H) return;
  int h = wid % H;
  float z = Z[(size_t)wid * 64 + lane];
  float vl = z * al[h * 64 + lane];
  float vr = z * ar[h * 64 + lane];
#pragma unroll
  for (int o = 32; o > 0; o >>= 1) { vl += __shfl_down(vl, o, 64); vr += __shfl_down(vr, o, 64); }
  if (lane == 0) { el[wid] = vl; er[wid] = vr; }
}

__global__ void k_scores4(const float* __restrict__ Z, const float* __restrict__ al,
                          const float* __restrict__ ar, float* __restrict__ el,
                          float* __restrict__ er) {
  int n = blockIdx.x * 256 + threadIdx.x;
  if (n >= NN) return;
  float4 z = *(const float4*)&Z[n * 4];
  el[n] = z.x * al[0] + z.y * al[1] + z.z * al[2] + z.w * al[3];
  er[n] = z.x * ar[0] + z.y * ar[1] + z.z * ar[2] + z.w * ar[3];
}

// ---- per-(dst,h): segment max, exp, sum ----
__global__ void k_mexp(const int* __restrict__ indptr, const int* __restrict__ csr,
                       const float* __restrict__ el, const float* __restrict__ er,
                       float* __restrict__ aex, float* __restrict__ sinv, int H) {
  int idx = blockIdx.x * 256 + threadIdx.x;
  if (idx >= NN * H) return;
  int n = idx / H, h = idx - n * H;
  int p0 = indptr[n], p1 = indptr[n + 1];
  float erv = er[idx];
  float m = -1e30f;
  for (int p = p0; p < p1; p++) {
    float e = el[csr[p] * H + h] + erv;
    e = (e > 0.f) ? e : 0.2f * e;
    m = fmaxf(m, e);
  }
  float s = 0.f;
  for (int p = p0; p < p1; p++) {
    float e = el[csr[p] * H + h] + erv;
    e = (e > 0.f) ? e : 0.2f * e;
    float x = __expf(e - m);
    aex[p * H + h] = x;
    s += x;
  }
  sinv[idx] = (p1 > p0) ? 1.f / s : 0.f;
}

// ---- aggregation: wave per (dst,h), lane = feature; fused bias + ELU ----
__global__ void k_agg(const int* __restrict__ indptr, const int* __restrict__ csr,
                      const float* __restrict__ aex, const float* __restrict__ sinv,
                      const float* __restrict__ Z, const float* __restrict__ bias,
                      float* __restrict__ outp, int H) {
  int g = blockIdx.x * 256 + threadIdx.x;
  int wid = g >> 6, lane = g & 63;
  if (wid >= NN * H) return;
  int n = wid / H, h = wid - n * H;
  int p0 = indptr[n], p1 = indptr[n + 1];
  float inv = sinv[wid];
  float acc = 0.f;
  for (int p = p0; p < p1; p++) {
    int s = csr[p];
    float a = aex[p * H + h];
    acc += a * Z[((size_t)s * H + h) * 64 + lane];
  }
  acc = acc * inv + bias[h * 64 + lane];
  acc = (acc > 0.f) ? acc : expm1f(acc);
  outp[(size_t)wid * 64 + lane] = acc;
}

// ---- final layer (H=1,F=4), writes d_out in detected dtype ----
__global__ void k_agg4(const int* __restrict__ indptr, const int* __restrict__ csr,
                       const float* __restrict__ aex, const float* __restrict__ sinv,
                       const float* __restrict__ Z, const float* __restrict__ bias,
                       void* __restrict__ outp, const int* __restrict__ flag) {
  int n = blockIdx.x * 256 + threadIdx.x;
  if (n >= NN) return;
  int p0 = indptr[n], p1 = indptr[n + 1];
  float inv = sinv[n];
  float ax = 0.f, ay = 0.f, az = 0.f, aw = 0.f;
  for (int p = p0; p < p1; p++) {
    int s = csr[p];
    float a = aex[p];
    float4 z = *(const float4*)&Z[s * 4];
    ax += a * z.x; ay += a * z.y; az += a * z.z; aw += a * z.w;
  }
  ax = ax * inv + bias[0]; ay = ay * inv + bias[1];
  az = az * inv + bias[2]; aw = aw * inv + bias[3];
  if (*flag) {
    unsigned short* o = (unsigned short*)outp;
    o[n * 4 + 0] = f2bf(ax); o[n * 4 + 1] = f2bf(ay);
    o[n * 4 + 2] = f2bf(az); o[n * 4 + 3] = f2bf(aw);
  } else {
    float* o = (float*)outp;
    o[n * 4 + 0] = ax; o[n * 4 + 1] = ay; o[n * 4 + 2] = az; o[n * 4 + 3] = aw;
  }
}

extern "C" void kernel_launch(void* const* d_in, const int* in_sizes, int n_in,
                              void* d_out, int out_size, void* d_ws, size_t ws_size,
                              hipStream_t stream) {
  (void)in_sizes; (void)n_in; (void)out_size; (void)ws_size;
  static const int fin[5] = {128, 256, 128, 128, 64};
  static const int Hh[5]  = {4, 2, 2, 1, 1};
  static const int HF[5]  = {256, 128, 128, 64, 4};

  char* ws = (char*)d_ws;
  size_t cur = 0;
  auto alloc = [&](size_t b) -> void* { void* p = ws + cur; cur += (b + 255) & ~(size_t)255; return p; };

  int*   flag   = (int*)alloc(4);
  int*   csum   = (int*)alloc(1024);
  int*   indptr = (int*)alloc((NN + 1) * 4);
  int*   fill   = (int*)alloc((size_t)NN * 4);
  int*   csr    = (int*)alloc((size_t)NE * 4);
  float* el     = (float*)alloc((size_t)NN * 4 * 4);
  float* er     = (float*)alloc((size_t)NN * 4 * 4);
  float* sinv   = (float*)alloc((size_t)NN * 4 * 4);
  float* aex    = (float*)alloc((size_t)NE * 4 * 4);
  float* xf     = (float*)alloc((size_t)NN * 128 * 4);
  float* smallf = (float*)alloc(100000 * 4);
  float* bufA   = (float*)alloc((size_t)NN * 256 * 4);
  float* bufB   = (float*)alloc((size_t)NN * 256 * 4);

  const int* srcIdx = (const int*)d_in[1];
  const int* dstIdx = (const int*)d_in[2];

  SmallPack pk;
  int off = 0;
  int Woff[5], aloff[5], aroff[5], boff[5];
  for (int i = 0; i < 5; i++) {
    pk.src[i * 4 + 0] = d_in[3 + i * 4 + 0]; pk.off[i * 4 + 0] = off; Woff[i]  = off; off += fin[i] * HF[i];
    pk.src[i * 4 + 1] = d_in[3 + i * 4 + 1]; pk.off[i * 4 + 1] = off; aloff[i] = off; off += HF[i];
    pk.src[i * 4 + 2] = d_in[3 + i * 4 + 2]; pk.off[i * 4 + 2] = off; aroff[i] = off; off += HF[i];
    pk.src[i * 4 + 3] = d_in[3 + i * 4 + 3]; pk.off[i * 4 + 3] = off; boff[i]  = off; off += HF[i];
  }
  pk.off[20] = off;
  int totalSmall = off;

  k_detect<<<1, 64, 0, stream>>>((const unsigned short*)d_in[0], flag);
  hipMemsetAsync(fill, 0, (size_t)NN * 4, stream);
  { int n = NN * 128; k_cvt<<<(n + 255) / 256, 256, 0, stream>>>(d_in[0], xf, n, flag); }
  k_cvt_small<<<(totalSmall + 255) / 256, 256, 0, stream>>>(pk, smallf, totalSmall, flag);
  k_count<<<(NE + 255) / 256, 256, 0, stream>>>(dstIdx, fill);
  int nch = (NN + 255) / 256;
  k_scan1<<<nch, 256, 0, stream>>>(fill, indptr, csum);
  k_scan2<<<1, 256, 0, stream>>>(csum, nch);
  k_scan3<<<nch, 256, 0, stream>>>(indptr, csum, fill);
  k_fill<<<(NE + 255) / 256, 256, 0, stream>>>(srcIdx, dstIdx, fill, csr);

  const float* hin = xf;
  for (int L = 0; L < 5; L++) {
    int K = fin[L], Nc = HF[L], H = Hh[L];
    const float* Wp  = smallf + Woff[L];
    const float* alp = smallf + aloff[L];
    const float* arp = smallf + aroff[L];
    const float* bp  = smallf + boff[L];
    dim3 gg((Nc + 63) / 64, (NN + 63) / 64);
    k_gemm<<<gg, 256, 0, stream>>>(hin, Wp, bufB, NN, K, Nc);
    if (L < 4) {
      int waves = NN * H;
      k_scores<<<(waves * 64 + 255) / 256, 256, 0, stream>>>(bufB, alp, arp, el, er, H);
      k_mexp<<<(waves + 255) / 256, 256, 0, stream>>>(indptr, csr, el, er, aex, sinv, H);
      k_agg<<<(waves * 64 + 255) / 256, 256, 0, stream>>>(indptr, csr, aex, sinv, bufB, bp, bufA, H);
      hin = bufA;
    } else {
      k_scores4<<<(NN + 255) / 256, 256, 0, stream>>>(bufB, alp, arp, el, er);
      k_mexp<<<(NN + 255) / 256, 256, 0, stream>>>(indptr, csr, el, er, aex, sinv, 1);
      k_agg4<<<(NN + 255) / 256, 256, 0, stream>>>(indptr, csr, aex, sinv, bufB, bp, d_out, flag);
    }
  }
}

// Round 2
// 760.506 us; speedup vs baseline: 1.5951x; 1.5951x over previous
//
#include <hip/hip_runtime.h>
#include <hip/hip_bf16.h>

#define NN 50000
#define NE 800000

__device__ __forceinline__ float bf2f(unsigned short u) {
  union { unsigned int i; float f; } v; v.i = ((unsigned int)u) << 16; return v.f;
}
__device__ __forceinline__ unsigned short f2bf(float f) {
  union { unsigned int i; float f; } v; v.f = f;
  unsigned int x = v.i;
  return (unsigned short)((x + 0x7FFFu + ((x >> 16) & 1u)) >> 16);
}

// ---- dtype probe ----
__global__ void k_detect(const unsigned short* __restrict__ xh, int* __restrict__ flag) {
  int t = threadIdx.x;
  float b0 = bf2f(xh[2 * t]);
  float b1 = bf2f(xh[2 * t + 1]);
  bool ok = (b0 == b0) && (b1 == b1) && fabsf(b0) < 64.f && fabsf(b1) < 64.f;
  unsigned long long m = __ballot(ok);
  if (t == 0) *flag = (m == ~0ull) ? 1 : 0;
}

__global__ void k_cvt(const void* __restrict__ src, float* __restrict__ dst, int n,
                      const int* __restrict__ flag) {
  int i = blockIdx.x * 256 + threadIdx.x;
  if (i >= n) return;
  if (*flag) dst[i] = bf2f(((const unsigned short*)src)[i]);
  else       dst[i] = ((const float*)src)[i];
}

struct SmallPack { const void* src[20]; int off[21]; };

__global__ void k_cvt_small(SmallPack pk, float* __restrict__ dst, int total,
                            const int* __restrict__ flag) {
  int i = blockIdx.x * 256 + threadIdx.x;
  if (i >= total) return;
  int d = 0;
  while (i >= pk.off[d + 1]) d++;
  int local = i - pk.off[d];
  if (*flag) dst[i] = bf2f(((const unsigned short*)pk.src[d])[local]);
  else       dst[i] = ((const float*)pk.src[d])[local];
}

// ---- CSR build ----
__global__ void k_count(const int* __restrict__ dst, int* __restrict__ fill) {
  int e = blockIdx.x * 256 + threadIdx.x;
  if (e < NE) atomicAdd(&fill[dst[e]], 1);
}

__global__ void k_scan1(const int* __restrict__ deg, int* __restrict__ outp, int* __restrict__ csum) {
  __shared__ int s[256];
  int t = threadIdx.x, i = blockIdx.x * 256 + t;
  int v = (i < NN) ? deg[i] : 0;
  s[t] = v; __syncthreads();
  for (int o = 1; o < 256; o <<= 1) {
    int x = (t >= o) ? s[t - o] : 0; __syncthreads();
    s[t] += x; __syncthreads();
  }
  if (i < NN) outp[i] = s[t] - v;
  if (t == 255) csum[blockIdx.x] = s[255];
}

__global__ void k_scan2(int* __restrict__ csum, int nc) {
  __shared__ int s[256];
  int t = threadIdx.x;
  int v = (t < nc) ? csum[t] : 0;
  s[t] = v; __syncthreads();
  for (int o = 1; o < 256; o <<= 1) {
    int x = (t >= o) ? s[t - o] : 0; __syncthreads();
    s[t] += x; __syncthreads();
  }
  if (t < nc) csum[t] = s[t] - v;
}

__global__ void k_scan3(int* __restrict__ indptr, const int* __restrict__ csum, int* __restrict__ fill) {
  int i = blockIdx.x * 256 + threadIdx.x;
  if (i < NN) { int v = indptr[i] + csum[blockIdx.x]; indptr[i] = v; fill[i] = v; }
  if (i == NN) indptr[NN] = NE;
}

__global__ void k_fill(const int* __restrict__ src, const int* __restrict__ dst,
                       int* __restrict__ fill, int* __restrict__ csr) {
  int e = blockIdx.x * 256 + threadIdx.x;
  if (e < NE) { int p = atomicAdd(&fill[dst[e]], 1); csr[p] = src[e]; }
}

// ---- fp32 GEMM: 128x64 tile, 8x4 micro, writes Z fp32 + Zh bf16 ----
__global__ __launch_bounds__(256) void k_gemm2(const float* __restrict__ A, const float* __restrict__ W,
                                               float* __restrict__ Z, unsigned short* __restrict__ Zh,
                                               int M, int K, int Nc) {
  __shared__ alignas(16) float As[32][132];  // [k][m]
  __shared__ alignas(16) float Bs[32][68];   // [k][n]
  int tid = threadIdx.x;
  int tx = tid & 15, ty = tid >> 4;
  int row0 = blockIdx.y * 128, col0 = blockIdx.x * 64;
  float acc[8][4] = {};
  for (int k0 = 0; k0 < K; k0 += 32) {
#pragma unroll
    for (int j = 0; j < 4; j++) {
      int v = tid + 256 * j;          // 0..1023
      int arow = v >> 3, aq = v & 7;  // row 0..127, k-quad 0..7
      float4 a = make_float4(0.f, 0.f, 0.f, 0.f);
      int grow = row0 + arow;
      if (grow < M) a = *(const float4*)&A[(size_t)grow * K + k0 + aq * 4];
      As[aq * 4 + 0][arow] = a.x; As[aq * 4 + 1][arow] = a.y;
      As[aq * 4 + 2][arow] = a.z; As[aq * 4 + 3][arow] = a.w;
    }
#pragma unroll
    for (int j = 0; j < 2; j++) {
      int v = tid + 256 * j;           // 0..511
      int brow = v >> 4, bq = v & 15;  // k 0..31, col-quad 0..15
      float4 b = make_float4(0.f, 0.f, 0.f, 0.f);
      int gcol = col0 + bq * 4;
      if (gcol < Nc) b = *(const float4*)&W[(size_t)(k0 + brow) * Nc + gcol];
      *(float4*)&Bs[brow][bq * 4] = b;
    }
    __syncthreads();
#pragma unroll
    for (int kk = 0; kk < 32; kk++) {
      float4 b4 = *(const float4*)&Bs[kk][tx * 4];
      float4 a0 = *(const float4*)&As[kk][ty * 8];
      float4 a1 = *(const float4*)&As[kk][ty * 8 + 4];
      float av[8] = {a0.x, a0.y, a0.z, a0.w, a1.x, a1.y, a1.z, a1.w};
      float bv[4] = {b4.x, b4.y, b4.z, b4.w};
#pragma unroll
      for (int i = 0; i < 8; i++)
#pragma unroll
        for (int jj = 0; jj < 4; jj++) acc[i][jj] += av[i] * bv[jj];
    }
    __syncthreads();
  }
#pragma unroll
  for (int i = 0; i < 8; i++) {
    int grow = row0 + ty * 8 + i;
    if (grow >= M) continue;
    int gcol = col0 + tx * 4;
    if (gcol < Nc) {
      *(float4*)&Z[(size_t)grow * Nc + gcol] = make_float4(acc[i][0], acc[i][1], acc[i][2], acc[i][3]);
      ushort4 h4;
      h4.x = f2bf(acc[i][0]); h4.y = f2bf(acc[i][1]);
      h4.z = f2bf(acc[i][2]); h4.w = f2bf(acc[i][3]);
      *(ushort4*)&Zh[(size_t)grow * Nc + gcol] = h4;
    }
  }
}

// ---- el/er: wave per (n,h), F=64 ----
__global__ void k_scores(const float* __restrict__ Z, const float* __restrict__ al,
                         const float* __restrict__ ar, float* __restrict__ el,
                         float* __restrict__ er, int H) {
  int g = blockIdx.x * 256 + threadIdx.x;
  int wid = g >> 6, lane = g & 63;
  if (wid >= NN * H) return;
  int h = wid % H;
  float z = Z[(size_t)wid * 64 + lane];
  float vl = z * al[h * 64 + lane];
  float vr = z * ar[h * 64 + lane];
#pragma unroll
  for (int o = 32; o > 0; o >>= 1) { vl += __shfl_down(vl, o, 64); vr += __shfl_down(vr, o, 64); }
  if (lane == 0) { el[wid] = vl; er[wid] = vr; }
}

__global__ void k_scores4(const float* __restrict__ Z, const float* __restrict__ al,
                          const float* __restrict__ ar, float* __restrict__ el,
                          float* __restrict__ er) {
  int n = blockIdx.x * 256 + threadIdx.x;
  if (n >= NN) return;
  float4 z = *(const float4*)&Z[n * 4];
  el[n] = z.x * al[0] + z.y * al[1] + z.z * al[2] + z.w * al[3];
  er[n] = z.x * ar[0] + z.y * ar[1] + z.z * ar[2] + z.w * ar[3];
}

// ---- softmax prep: wave per dst, lanes = (edge j, head h) ----
template <int H>
__global__ void k_mexp_w(const int* __restrict__ indptr, const int* __restrict__ csr,
                         const float* __restrict__ el, const float* __restrict__ er,
                         float* __restrict__ aex, float* __restrict__ sinv) {
  int g = blockIdx.x * 256 + threadIdx.x;
  int n = g >> 6, lane = g & 63;
  if (n >= NN) return;
  const int EP = 64 / H;
  int j = lane >> (H == 4 ? 2 : (H == 2 ? 1 : 0));
  int h = lane & (H - 1);
  int p0 = indptr[n], p1 = indptr[n + 1];
  float erv = er[n * H + h];
  float m = -1e30f;
  for (int p = p0 + j; p < p1; p += EP) {
    float e = el[csr[p] * H + h] + erv;
    e = (e > 0.f) ? e : 0.2f * e;
    m = fmaxf(m, e);
  }
#pragma unroll
  for (int o = H; o < 64; o <<= 1) m = fmaxf(m, __shfl_xor(m, o, 64));
  float s = 0.f;
  for (int p = p0 + j; p < p1; p += EP) {
    float e = el[csr[p] * H + h] + erv;
    e = (e > 0.f) ? e : 0.2f * e;
    float x = __expf(e - m);
    aex[p * H + h] = x;
    s += x;
  }
#pragma unroll
  for (int o = H; o < 64; o <<= 1) s += __shfl_xor(s, o, 64);
  if (lane < H) sinv[n * H + lane] = (p1 > p0) ? 1.f / s : 0.f;
}

// ---- aggregation: wave per dst, all heads, bf16 Z gather, fused bias+ELU ----
template <int HF, int H>
__global__ void k_agg_bf(const int* __restrict__ indptr, const int* __restrict__ csr,
                         const float* __restrict__ aex, const float* __restrict__ sinv,
                         const unsigned short* __restrict__ Zh, const float* __restrict__ bias,
                         float* __restrict__ outp) {
  const int LPE = HF / 8;   // lanes per edge
  const int EPI = 64 / LPE; // edges per iteration
  int g = blockIdx.x * 256 + threadIdx.x;
  int n = g >> 6, lane = g & 63;
  if (n >= NN) return;
  int grp = lane / LPE;
  int fl = lane % LPE;
  int f0 = fl * 8;
  int h = f0 >> 6;
  int p0 = indptr[n], p1 = indptr[n + 1];
  float acc[8] = {};
#define AGG_BODY(P)                                                         \
  {                                                                         \
    int s_ = csr[P];                                                        \
    float a_ = aex[(P) * H + h];                                            \
    uint4 v_ = *(const uint4*)(Zh + (size_t)s_ * HF + f0);                  \
    unsigned int w_[4] = {v_.x, v_.y, v_.z, v_.w};                          \
    _Pragma("unroll") for (int q = 0; q < 4; q++) {                         \
      acc[2 * q]     += a_ * bf2f((unsigned short)(w_[q] & 0xffffu));       \
      acc[2 * q + 1] += a_ * bf2f((unsigned short)(w_[q] >> 16));           \
    }                                                                       \
  }
  int p = p0 + grp;
  for (; p + EPI < p1; p += 2 * EPI) { AGG_BODY(p); AGG_BODY(p + EPI); }
  if (p < p1) AGG_BODY(p);
#undef AGG_BODY
#pragma unroll
  for (int o = LPE; o < 64; o <<= 1) {
#pragma unroll
    for (int i = 0; i < 8; i++) acc[i] += __shfl_xor(acc[i], o, 64);
  }
  if (grp == 0) {
    float inv = sinv[n * H + h];
    float r[8];
#pragma unroll
    for (int i = 0; i < 8; i++) {
      float x = acc[i] * inv + bias[f0 + i];
      r[i] = (x > 0.f) ? x : expm1f(x);
    }
    *(float4*)&outp[(size_t)n * HF + f0]     = make_float4(r[0], r[1], r[2], r[3]);
    *(float4*)&outp[(size_t)n * HF + f0 + 4] = make_float4(r[4], r[5], r[6], r[7]);
  }
}

// ---- final layer (H=1,F=4) ----
__global__ void k_agg4(const int* __restrict__ indptr, const int* __restrict__ csr,
                       const float* __restrict__ aex, const float* __restrict__ sinv,
                       const float* __restrict__ Z, const float* __restrict__ bias,
                       void* __restrict__ outp, const int* __restrict__ flag) {
  int n = blockIdx.x * 256 + threadIdx.x;
  if (n >= NN) return;
  int p0 = indptr[n], p1 = indptr[n + 1];
  float inv = sinv[n];
  float ax = 0.f, ay = 0.f, az = 0.f, aw = 0.f;
  for (int p = p0; p < p1; p++) {
    int s = csr[p];
    float a = aex[p];
    float4 z = *(const float4*)&Z[s * 4];
    ax += a * z.x; ay += a * z.y; az += a * z.z; aw += a * z.w;
  }
  ax = ax * inv + bias[0]; ay = ay * inv + bias[1];
  az = az * inv + bias[2]; aw = aw * inv + bias[3];
  if (*flag) {
    unsigned short* o = (unsigned short*)outp;
    o[n * 4 + 0] = f2bf(ax); o[n * 4 + 1] = f2bf(ay);
    o[n * 4 + 2] = f2bf(az); o[n * 4 + 3] = f2bf(aw);
  } else {
    float* o = (float*)outp;
    o[n * 4 + 0] = ax; o[n * 4 + 1] = ay; o[n * 4 + 2] = az; o[n * 4 + 3] = aw;
  }
}

extern "C" void kernel_launch(void* const* d_in, const int* in_sizes, int n_in,
                              void* d_out, int out_size, void* d_ws, size_t ws_size,
                              hipStream_t stream) {
  (void)in_sizes; (void)n_in; (void)out_size; (void)ws_size;
  static const int fin[5] = {128, 256, 128, 128, 64};
  static const int Hh[5]  = {4, 2, 2, 1, 1};
  static const int HF[5]  = {256, 128, 128, 64, 4};

  char* ws = (char*)d_ws;
  size_t cur = 0;
  auto alloc = [&](size_t b) -> void* { void* p = ws + cur; cur += (b + 255) & ~(size_t)255; return p; };

  int*   flag   = (int*)alloc(4);
  int*   csum   = (int*)alloc(1024);
  int*   indptr = (int*)alloc((NN + 1) * 4);
  int*   fill   = (int*)alloc((size_t)NN * 4);
  int*   csr    = (int*)alloc((size_t)NE * 4);
  float* el     = (float*)alloc((size_t)NN * 4 * 4);
  float* er     = (float*)alloc((size_t)NN * 4 * 4);
  float* sinv   = (float*)alloc((size_t)NN * 4 * 4);
  float* aex    = (float*)alloc((size_t)NE * 4 * 4);
  float* xf     = (float*)alloc((size_t)NN * 128 * 4);
  float* smallf = (float*)alloc(100000 * 4);
  float* bufA   = (float*)alloc((size_t)NN * 256 * 4);
  float* bufB   = (float*)alloc((size_t)NN * 256 * 4);
  unsigned short* zh = (unsigned short*)alloc((size_t)NN * 256 * 2);

  const int* srcIdx = (const int*)d_in[1];
  const int* dstIdx = (const int*)d_in[2];

  SmallPack pk;
  int off = 0;
  int Woff[5], aloff[5], aroff[5], boff[5];
  for (int i = 0; i < 5; i++) {
    pk.src[i * 4 + 0] = d_in[3 + i * 4 + 0]; pk.off[i * 4 + 0] = off; Woff[i]  = off; off += fin[i] * HF[i];
    pk.src[i * 4 + 1] = d_in[3 + i * 4 + 1]; pk.off[i * 4 + 1] = off; aloff[i] = off; off += HF[i];
    pk.src[i * 4 + 2] = d_in[3 + i * 4 + 2]; pk.off[i * 4 + 2] = off; aroff[i] = off; off += HF[i];
    pk.src[i * 4 + 3] = d_in[3 + i * 4 + 3]; pk.off[i * 4 + 3] = off; boff[i]  = off; off += HF[i];
  }
  pk.off[20] = off;
  int totalSmall = off;

  k_detect<<<1, 64, 0, stream>>>((const unsigned short*)d_in[0], flag);
  hipMemsetAsync(fill, 0, (size_t)NN * 4, stream);
  { int n = NN * 128; k_cvt<<<(n + 255) / 256, 256, 0, stream>>>(d_in[0], xf, n, flag); }
  k_cvt_small<<<(totalSmall + 255) / 256, 256, 0, stream>>>(pk, smallf, totalSmall, flag);
  k_count<<<(NE + 255) / 256, 256, 0, stream>>>(dstIdx, fill);
  int nch = (NN + 255) / 256;
  k_scan1<<<nch, 256, 0, stream>>>(fill, indptr, csum);
  k_scan2<<<1, 256, 0, stream>>>(csum, nch);
  k_scan3<<<nch, 256, 0, stream>>>(indptr, csum, fill);
  k_fill<<<(NE + 255) / 256, 256, 0, stream>>>(srcIdx, dstIdx, fill, csr);

  const int nwaveblk = (NN * 64 + 255) / 256;  // wave-per-dst kernels

  const float* hin = xf;
  for (int L = 0; L < 5; L++) {
    int K = fin[L], Nc = HF[L], H = Hh[L];
    const float* Wp  = smallf + Woff[L];
    const float* alp = smallf + aloff[L];
    const float* arp = smallf + aroff[L];
    const float* bp  = smallf + boff[L];
    dim3 gg((Nc + 63) / 64, (NN + 127) / 128);
    k_gemm2<<<gg, 256, 0, stream>>>(hin, Wp, bufB, zh, NN, K, Nc);
    if (L < 4) {
      int waves = NN * H;
      k_scores<<<(waves * 64 + 255) / 256, 256, 0, stream>>>(bufB, alp, arp, el, er, H);
      if (H == 4)      k_mexp_w<4><<<nwaveblk, 256, 0, stream>>>(indptr, csr, el, er, aex, sinv);
      else if (H == 2) k_mexp_w<2><<<nwaveblk, 256, 0, stream>>>(indptr, csr, el, er, aex, sinv);
      else             k_mexp_w<1><<<nwaveblk, 256, 0, stream>>>(indptr, csr, el, er, aex, sinv);
      if (L == 0)      k_agg_bf<256, 4><<<nwaveblk, 256, 0, stream>>>(indptr, csr, aex, sinv, zh, bp, bufA);
      else if (L == 3) k_agg_bf<64, 1><<<nwaveblk, 256, 0, stream>>>(indptr, csr, aex, sinv, zh, bp, bufA);
      else             k_agg_bf<128, 2><<<nwaveblk, 256, 0, stream>>>(indptr, csr, aex, sinv, zh, bp, bufA);
      hin = bufA;
    } else {
      k_scores4<<<(NN + 255) / 256, 256, 0, stream>>>(bufB, alp, arp, el, er);
      k_mexp_w<1><<<nwaveblk, 256, 0, stream>>>(indptr, csr, el, er, aex, sinv);
      k_agg4<<<(NN + 255) / 256, 256, 0, stream>>>(indptr, csr, aex, sinv, bufB, bp, d_out, flag);
    }
  }
}

// Round 3
// 602.591 us; speedup vs baseline: 2.0131x; 1.2621x over previous
//
#include <hip/hip_runtime.h>
#include <hip/hip_bf16.h>

#define NN 50000
#define NE 800000

typedef __attribute__((ext_vector_type(8))) short s16x8;
typedef __attribute__((ext_vector_type(4))) float f32x4;

__device__ __forceinline__ float bf2f(unsigned short u) {
  union { unsigned int i; float f; } v; v.i = ((unsigned int)u) << 16; return v.f;
}
__device__ __forceinline__ unsigned short f2bf(float f) {
  union { unsigned int i; float f; } v; v.f = f;
  unsigned int x = v.i;
  return (unsigned short)((x + 0x7FFFu + ((x >> 16) & 1u)) >> 16);
}

// ---- dtype probe ----
__global__ void k_detect(const unsigned short* __restrict__ xh, int* __restrict__ flag) {
  int t = threadIdx.x;
  float b0 = bf2f(xh[2 * t]);
  float b1 = bf2f(xh[2 * t + 1]);
  bool ok = (b0 == b0) && (b1 == b1) && fabsf(b0) < 64.f && fabsf(b1) < 64.f;
  unsigned long long m = __ballot(ok);
  if (t == 0) *flag = (m == ~0ull) ? 1 : 0;
}

// ---- x -> bf16 buffer (copy-through if already bf16) ----
__global__ void k_cvt_x(const void* __restrict__ src, unsigned short* __restrict__ dst, int n,
                        const int* __restrict__ flag) {
  int i = blockIdx.x * 256 + threadIdx.x;
  if (i >= n) return;
  if (*flag) dst[i] = ((const unsigned short*)src)[i];
  else       dst[i] = f2bf(((const float*)src)[i]);
}

struct SmallPack { const void* src[20]; int off[21]; };

__global__ void k_cvt_small(SmallPack pk, float* __restrict__ dst, int total,
                            const int* __restrict__ flag) {
  int i = blockIdx.x * 256 + threadIdx.x;
  if (i >= total) return;
  int d = 0;
  while (i >= pk.off[d + 1]) d++;
  int local = i - pk.off[d];
  if (*flag) dst[i] = bf2f(((const unsigned short*)pk.src[d])[local]);
  else       dst[i] = ((const float*)pk.src[d])[local];
}

// ---- W -> W^T bf16 (per-layer, pow2 dims) ----
struct WPack { const void* w[5]; };

__global__ void k_prep_w(WPack wp, unsigned short* __restrict__ wt, const int* __restrict__ flag) {
  const int KN[5]   = {32768, 32768, 16384, 8192, 256};
  const int LGN[5]  = {8, 7, 7, 6, 2};
  const int KK[5]   = {128, 256, 128, 128, 64};
  const int OFF[5]  = {0, 32768, 65536, 81920, 90112};
  int l = blockIdx.y;
  int i = blockIdx.x * 256 + threadIdx.x;
  if (i >= KN[l]) return;
  int k = i >> LGN[l];
  int n = i & ((1 << LGN[l]) - 1);
  unsigned short v;
  if (*flag) v = ((const unsigned short*)wp.w[l])[i];
  else       v = f2bf(((const float*)wp.w[l])[i]);
  wt[OFF[l] + n * KK[l] + k] = v;
}

// ---- CSR build ----
__global__ void k_count(const int* __restrict__ dst, int* __restrict__ fill) {
  int e = blockIdx.x * 256 + threadIdx.x;
  if (e < NE) atomicAdd(&fill[dst[e]], 1);
}

__global__ void k_scan1(const int* __restrict__ deg, int* __restrict__ outp, int* __restrict__ csum) {
  __shared__ int s[256];
  int t = threadIdx.x, i = blockIdx.x * 256 + t;
  int v = (i < NN) ? deg[i] : 0;
  s[t] = v; __syncthreads();
  for (int o = 1; o < 256; o <<= 1) {
    int x = (t >= o) ? s[t - o] : 0; __syncthreads();
    s[t] += x; __syncthreads();
  }
  if (i < NN) outp[i] = s[t] - v;
  if (t == 255) csum[blockIdx.x] = s[255];
}

__global__ void k_scan2(int* __restrict__ csum, int nc) {
  __shared__ int s[256];
  int t = threadIdx.x;
  int v = (t < nc) ? csum[t] : 0;
  s[t] = v; __syncthreads();
  for (int o = 1; o < 256; o <<= 1) {
    int x = (t >= o) ? s[t - o] : 0; __syncthreads();
    s[t] += x; __syncthreads();
  }
  if (t < nc) csum[t] = s[t] - v;
}

__global__ void k_scan3(int* __restrict__ indptr, const int* __restrict__ csum, int* __restrict__ fill) {
  int i = blockIdx.x * 256 + threadIdx.x;
  if (i < NN) { int v = indptr[i] + csum[blockIdx.x]; indptr[i] = v; fill[i] = v; }
  if (i == NN) indptr[NN] = NE;
}

__global__ void k_fill(const int* __restrict__ src, const int* __restrict__ dst,
                       int* __restrict__ fill, int* __restrict__ csr) {
  int e = blockIdx.x * 256 + threadIdx.x;
  if (e < NE) { int p = atomicAdd(&fill[dst[e]], 1); csr[p] = src[e]; }
}

// ---- bf16 MFMA GEMM: Zh[M][Nc] = A[M][K] * Wt^T, fused el/er epilogue ----
// BM=64, BN=64 (= one head), BK=32; 4 waves, wave w owns rows [16w,16w+16).
__global__ __launch_bounds__(256) void k_gemm_mfma(const unsigned short* __restrict__ A,
                                                   const unsigned short* __restrict__ Wt,
                                                   unsigned short* __restrict__ Zh,
                                                   const float* __restrict__ al,
                                                   const float* __restrict__ ar,
                                                   float* __restrict__ el, float* __restrict__ er,
                                                   int M, int K, int Nc, int H) {
  __shared__ unsigned short As[64][40];  // +8 pad: 80B row stride, 16B-aligned
  int tid = threadIdx.x;
  int w = tid >> 6, l = tid & 63;
  int l15 = l & 15, l16 = l >> 4;
  int row0 = blockIdx.y * 64, col0 = blockIdx.x * 64;
  int h = blockIdx.x;  // BN == 64 == one head's F
  f32x4 acc[4] = {};
  for (int k0 = 0; k0 < K; k0 += 32) {
    int r = tid >> 2, kq = tid & 3;
    int grow = row0 + r;
    uint4 av = make_uint4(0, 0, 0, 0);
    if (grow < M) av = *(const uint4*)&A[(size_t)grow * K + k0 + kq * 8];
    *(uint4*)&As[r][kq * 8] = av;
    __syncthreads();
    s16x8 afrag = *(const s16x8*)&As[w * 16 + l15][l16 * 8];
#pragma unroll
    for (int nt = 0; nt < 4; nt++) {
      s16x8 bfrag = *(const s16x8*)&Wt[(size_t)(col0 + nt * 16 + l15) * K + k0 + l16 * 8];
      acc[nt] = __builtin_amdgcn_mfma_f32_16x16x32_bf16(afrag, bfrag, acc[nt], 0, 0, 0);
    }
    __syncthreads();
  }
  // epilogue: Zh store + fused el/er
  float alv[4], arv[4];
#pragma unroll
  for (int nt = 0; nt < 4; nt++) {
    alv[nt] = al[h * 64 + nt * 16 + l15];
    arv[nt] = ar[h * 64 + nt * 16 + l15];
  }
#pragma unroll
  for (int r = 0; r < 4; r++) {
    int mrow = w * 16 + l16 * 4 + r;
    int grow = row0 + mrow;
    bool ok = grow < M;
    float vl = 0.f, vr = 0.f;
#pragma unroll
    for (int nt = 0; nt < 4; nt++) {
      float a = acc[nt][r];
      if (ok) Zh[(size_t)grow * Nc + col0 + nt * 16 + l15] = f2bf(a);
      vl += a * alv[nt];
      vr += a * arv[nt];
    }
#pragma unroll
    for (int o = 1; o < 16; o <<= 1) {
      vl += __shfl_xor(vl, o, 64);
      vr += __shfl_xor(vr, o, 64);
    }
    if (l15 == 0 && ok) {
      el[grow * H + h] = vl;
      er[grow * H + h] = vr;
    }
  }
}

// ---- softmax prep: wave per dst, lanes = (edge j, head h) ----
template <int H>
__global__ void k_mexp_w(const int* __restrict__ indptr, const int* __restrict__ csr,
                         const float* __restrict__ el, const float* __restrict__ er,
                         float* __restrict__ aex, float* __restrict__ sinv) {
  int g = blockIdx.x * 256 + threadIdx.x;
  int n = g >> 6, lane = g & 63;
  if (n >= NN) return;
  const int EP = 64 / H;
  int j = lane >> (H == 4 ? 2 : (H == 2 ? 1 : 0));
  int h = lane & (H - 1);
  int p0 = indptr[n], p1 = indptr[n + 1];
  float erv = er[n * H + h];
  float m = -1e30f;
  for (int p = p0 + j; p < p1; p += EP) {
    float e = el[csr[p] * H + h] + erv;
    e = (e > 0.f) ? e : 0.2f * e;
    m = fmaxf(m, e);
  }
#pragma unroll
  for (int o = H; o < 64; o <<= 1) m = fmaxf(m, __shfl_xor(m, o, 64));
  float s = 0.f;
  for (int p = p0 + j; p < p1; p += EP) {
    float e = el[csr[p] * H + h] + erv;
    e = (e > 0.f) ? e : 0.2f * e;
    float x = __expf(e - m);
    aex[p * H + h] = x;
    s += x;
  }
#pragma unroll
  for (int o = H; o < 64; o <<= 1) s += __shfl_xor(s, o, 64);
  if (lane < H) sinv[n * H + lane] = (p1 > p0) ? 1.f / s : 0.f;
}

// ---- aggregation: wave per dst, bf16 gather, fused bias+ELU, bf16 out ----
template <int HF, int H>
__global__ void k_agg_bf(const int* __restrict__ indptr, const int* __restrict__ csr,
                         const float* __restrict__ aex, const float* __restrict__ sinv,
                         const unsigned short* __restrict__ Zh, const float* __restrict__ bias,
                         unsigned short* __restrict__ outp) {
  const int LPE = HF / 8;   // lanes per edge
  const int EPI = 64 / LPE; // edges in flight
  int g = blockIdx.x * 256 + threadIdx.x;
  int n = g >> 6, lane = g & 63;
  if (n >= NN) return;
  int grp = lane / LPE;
  int fl = lane % LPE;
  int f0 = fl * 8;
  int h = f0 >> 6;
  int p0 = indptr[n], p1 = indptr[n + 1];
  float acc[8] = {};
#define AGG_BODY(P)                                                         \
  {                                                                         \
    int s_ = csr[P];                                                        \
    float a_ = aex[(P) * H + h];                                            \
    uint4 v_ = *(const uint4*)(Zh + (size_t)s_ * HF + f0);                  \
    unsigned int w_[4] = {v_.x, v_.y, v_.z, v_.w};                          \
    _Pragma("unroll") for (int q = 0; q < 4; q++) {                         \
      acc[2 * q]     += a_ * bf2f((unsigned short)(w_[q] & 0xffffu));       \
      acc[2 * q + 1] += a_ * bf2f((unsigned short)(w_[q] >> 16));           \
    }                                                                       \
  }
  int p = p0 + grp;
  for (; p + EPI < p1; p += 2 * EPI) { AGG_BODY(p); AGG_BODY(p + EPI); }
  if (p < p1) AGG_BODY(p);
#undef AGG_BODY
#pragma unroll
  for (int o = LPE; o < 64; o <<= 1) {
#pragma unroll
    for (int i = 0; i < 8; i++) acc[i] += __shfl_xor(acc[i], o, 64);
  }
  if (grp == 0) {
    float inv = sinv[n * H + h];
    unsigned int pk[4];
#pragma unroll
    for (int q = 0; q < 4; q++) {
      float x0 = acc[2 * q] * inv + bias[f0 + 2 * q];
      float x1 = acc[2 * q + 1] * inv + bias[f0 + 2 * q + 1];
      x0 = (x0 > 0.f) ? x0 : expm1f(x0);
      x1 = (x1 > 0.f) ? x1 : expm1f(x1);
      pk[q] = (unsigned int)f2bf(x0) | ((unsigned int)f2bf(x1) << 16);
    }
    *(uint4*)&outp[(size_t)n * HF + f0] = make_uint4(pk[0], pk[1], pk[2], pk[3]);
  }
}

// ---- layer 5 linear (K=64 -> 4) + scores, fp32 compute from bf16 in ----
__global__ void k_l5(const unsigned short* __restrict__ hb, const float* __restrict__ W5,
                     const float* __restrict__ al5, const float* __restrict__ ar5,
                     float* __restrict__ z5, float* __restrict__ el, float* __restrict__ er) {
  __shared__ float W5s[256];
  int t = threadIdx.x;
  W5s[t] = W5[t];
  __syncthreads();
  int n = blockIdx.x * 256 + t;
  if (n >= NN) return;
  float z[4] = {};
#pragma unroll
  for (int kq = 0; kq < 8; kq++) {
    uint4 v = *(const uint4*)&hb[(size_t)n * 64 + kq * 8];
    unsigned int w_[4] = {v.x, v.y, v.z, v.w};
#pragma unroll
    for (int q = 0; q < 4; q++) {
      float f0 = bf2f((unsigned short)(w_[q] & 0xffffu));
      float f1 = bf2f((unsigned short)(w_[q] >> 16));
      int k = kq * 8 + 2 * q;
#pragma unroll
      for (int c = 0; c < 4; c++) z[c] += f0 * W5s[k * 4 + c] + f1 * W5s[(k + 1) * 4 + c];
    }
  }
  el[n] = z[0] * al5[0] + z[1] * al5[1] + z[2] * al5[2] + z[3] * al5[3];
  er[n] = z[0] * ar5[0] + z[1] * ar5[1] + z[2] * ar5[2] + z[3] * ar5[3];
  *(float4*)&z5[n * 4] = make_float4(z[0], z[1], z[2], z[3]);
}

// ---- final aggregation (H=1,F=4) ----
__global__ void k_agg4(const int* __restrict__ indptr, const int* __restrict__ csr,
                       const float* __restrict__ aex, const float* __restrict__ sinv,
                       const float* __restrict__ Z, const float* __restrict__ bias,
                       void* __restrict__ outp, const int* __restrict__ flag) {
  int n = blockIdx.x * 256 + threadIdx.x;
  if (n >= NN) return;
  int p0 = indptr[n], p1 = indptr[n + 1];
  float inv = sinv[n];
  float ax = 0.f, ay = 0.f, az = 0.f, aw = 0.f;
  for (int p = p0; p < p1; p++) {
    int s = csr[p];
    float a = aex[p];
    float4 z = *(const float4*)&Z[s * 4];
    ax += a * z.x; ay += a * z.y; az += a * z.z; aw += a * z.w;
  }
  ax = ax * inv + bias[0]; ay = ay * inv + bias[1];
  az = az * inv + bias[2]; aw = aw * inv + bias[3];
  if (*flag) {
    unsigned short* o = (unsigned short*)outp;
    o[n * 4 + 0] = f2bf(ax); o[n * 4 + 1] = f2bf(ay);
    o[n * 4 + 2] = f2bf(az); o[n * 4 + 3] = f2bf(aw);
  } else {
    float* o = (float*)outp;
    o[n * 4 + 0] = ax; o[n * 4 + 1] = ay; o[n * 4 + 2] = az; o[n * 4 + 3] = aw;
  }
}

extern "C" void kernel_launch(void* const* d_in, const int* in_sizes, int n_in,
                              void* d_out, int out_size, void* d_ws, size_t ws_size,
                              hipStream_t stream) {
  (void)in_sizes; (void)n_in; (void)out_size; (void)ws_size;
  static const int fin[5] = {128, 256, 128, 128, 64};
  static const int Hh[5]  = {4, 2, 2, 1, 1};
  static const int HF[5]  = {256, 128, 128, 64, 4};
  static const int WtOff[5] = {0, 32768, 65536, 81920, 90112};

  char* ws = (char*)d_ws;
  size_t cur = 0;
  auto alloc = [&](size_t b) -> void* { void* p = ws + cur; cur += (b + 255) & ~(size_t)255; return p; };

  int*   flag   = (int*)alloc(4);
  int*   csum   = (int*)alloc(1024);
  int*   indptr = (int*)alloc((NN + 1) * 4);
  int*   fill   = (int*)alloc((size_t)NN * 4);
  int*   csr    = (int*)alloc((size_t)NE * 4);
  float* el     = (float*)alloc((size_t)NN * 4 * 4);
  float* er     = (float*)alloc((size_t)NN * 4 * 4);
  float* sinv   = (float*)alloc((size_t)NN * 4 * 4);
  float* aex    = (float*)alloc((size_t)NE * 4 * 4);
  float* smallf = (float*)alloc(100000 * 4);
  unsigned short* xh   = (unsigned short*)alloc((size_t)NN * 128 * 2);
  unsigned short* wt   = (unsigned short*)alloc(90368 * 2);
  unsigned short* hb0  = (unsigned short*)alloc((size_t)NN * 256 * 2);
  unsigned short* hb1  = (unsigned short*)alloc((size_t)NN * 256 * 2);
  unsigned short* zh   = (unsigned short*)alloc((size_t)NN * 256 * 2);
  float* z5     = (float*)alloc((size_t)NN * 4 * 4);

  const int* srcIdx = (const int*)d_in[1];
  const int* dstIdx = (const int*)d_in[2];

  SmallPack pk;
  WPack wpk;
  int off = 0;
  int aloff[5], aroff[5], boff[5], w5off = 0;
  for (int i = 0; i < 5; i++) {
    pk.src[i * 4 + 0] = d_in[3 + i * 4 + 0]; pk.off[i * 4 + 0] = off;
    wpk.w[i] = d_in[3 + i * 4 + 0];
    if (i == 4) w5off = off;
    off += fin[i] * HF[i];
    pk.src[i * 4 + 1] = d_in[3 + i * 4 + 1]; pk.off[i * 4 + 1] = off; aloff[i] = off; off += HF[i];
    pk.src[i * 4 + 2] = d_in[3 + i * 4 + 2]; pk.off[i * 4 + 2] = off; aroff[i] = off; off += HF[i];
    pk.src[i * 4 + 3] = d_in[3 + i * 4 + 3]; pk.off[i * 4 + 3] = off; boff[i]  = off; off += HF[i];
  }
  pk.off[20] = off;
  int totalSmall = off;

  k_detect<<<1, 64, 0, stream>>>((const unsigned short*)d_in[0], flag);
  hipMemsetAsync(fill, 0, (size_t)NN * 4, stream);
  { int n = NN * 128; k_cvt_x<<<(n + 255) / 256, 256, 0, stream>>>(d_in[0], xh, n, flag); }
  k_cvt_small<<<(totalSmall + 255) / 256, 256, 0, stream>>>(pk, smallf, totalSmall, flag);
  { dim3 g(128, 5); k_prep_w<<<g, 256, 0, stream>>>(wpk, wt, flag); }
  k_count<<<(NE + 255) / 256, 256, 0, stream>>>(dstIdx, fill);
  int nch = (NN + 255) / 256;
  k_scan1<<<nch, 256, 0, stream>>>(fill, indptr, csum);
  k_scan2<<<1, 256, 0, stream>>>(csum, nch);
  k_scan3<<<nch, 256, 0, stream>>>(indptr, csum, fill);
  k_fill<<<(NE + 255) / 256, 256, 0, stream>>>(srcIdx, dstIdx, fill, csr);

  const int nwaveblk = (NN * 64 + 255) / 256;

  const unsigned short* hin = xh;
  unsigned short* hout = hb0;
  for (int L = 0; L < 4; L++) {
    int K = fin[L], Nc = HF[L], H = Hh[L];
    const float* alp = smallf + aloff[L];
    const float* arp = smallf + aroff[L];
    const float* bp  = smallf + boff[L];
    dim3 gg(Nc / 64, (NN + 63) / 64);
    k_gemm_mfma<<<gg, 256, 0, stream>>>(hin, wt + WtOff[L], zh, alp, arp, el, er, NN, K, Nc, H);
    if (H == 4)      k_mexp_w<4><<<nwaveblk, 256, 0, stream>>>(indptr, csr, el, er, aex, sinv);
    else if (H == 2) k_mexp_w<2><<<nwaveblk, 256, 0, stream>>>(indptr, csr, el, er, aex, sinv);
    else             k_mexp_w<1><<<nwaveblk, 256, 0, stream>>>(indptr, csr, el, er, aex, sinv);
    if (L == 0)      k_agg_bf<256, 4><<<nwaveblk, 256, 0, stream>>>(indptr, csr, aex, sinv, zh, bp, hout);
    else if (L == 3) k_agg_bf<64, 1><<<nwaveblk, 256, 0, stream>>>(indptr, csr, aex, sinv, zh, bp, hout);
    else             k_agg_bf<128, 2><<<nwaveblk, 256, 0, stream>>>(indptr, csr, aex, sinv, zh, bp, hout);
    hin = hout;
    hout = (hout == hb0) ? hb1 : hb0;
  }
  // layer 5
  k_l5<<<(NN + 255) / 256, 256, 0, stream>>>(hin, smallf + w5off, smallf + aloff[4],
                                             smallf + aroff[4], z5, el, er);
  k_mexp_w<1><<<nwaveblk, 256, 0, stream>>>(indptr, csr, el, er, aex, sinv);
  k_agg4<<<(NN + 255) / 256, 256, 0, stream>>>(indptr, csr, aex, sinv, z5, smallf + boff[4], d_out, flag);
}

// Round 8
// 524.568 us; speedup vs baseline: 2.3125x; 1.1487x over previous
//
#include <hip/hip_runtime.h>
#include <hip/hip_bf16.h>

#define NN 50000
#define NE 800000

typedef __attribute__((ext_vector_type(8))) short s16x8;
typedef __attribute__((ext_vector_type(4))) float f32x4;

__device__ __forceinline__ float bf2f(unsigned short u) {
  union { unsigned int i; float f; } v; v.i = ((unsigned int)u) << 16; return v.f;
}
__device__ __forceinline__ unsigned short f2bf(float f) {
  union { unsigned int i; float f; } v; v.f = f;
  unsigned int x = v.i;
  return (unsigned short)((x + 0x7FFFu + ((x >> 16) & 1u)) >> 16);
}

// ---- dtype probe ----
__global__ void k_detect(const unsigned short* __restrict__ xh, int* __restrict__ flag) {
  int t = threadIdx.x;
  float b0 = bf2f(xh[2 * t]);
  float b1 = bf2f(xh[2 * t + 1]);
  bool ok = (b0 == b0) && (b1 == b1) && fabsf(b0) < 64.f && fabsf(b1) < 64.f;
  unsigned long long m = __ballot(ok);
  if (t == 0) *flag = (m == ~0ull) ? 1 : 0;
}

// ---- x -> bf16 buffer ----
__global__ void k_cvt_x(const void* __restrict__ src, unsigned short* __restrict__ dst, int n,
                        const int* __restrict__ flag) {
  int i = blockIdx.x * 256 + threadIdx.x;
  if (i >= n) return;
  if (*flag) dst[i] = ((const unsigned short*)src)[i];
  else       dst[i] = f2bf(((const float*)src)[i]);
}

struct SmallPack { const void* src[20]; int off[21]; };

__global__ void k_cvt_small(SmallPack pk, float* __restrict__ dst, int total,
                            const int* __restrict__ flag) {
  int i = blockIdx.x * 256 + threadIdx.x;
  if (i >= total) return;
  int d = 0;
  while (i >= pk.off[d + 1]) d++;
  int local = i - pk.off[d];
  if (*flag) dst[i] = bf2f(((const unsigned short*)pk.src[d])[local]);
  else       dst[i] = ((const float*)pk.src[d])[local];
}

// ---- W -> W^T bf16 ----
struct WPack { const void* w[5]; };

__global__ void k_prep_w(WPack wp, unsigned short* __restrict__ wt, const int* __restrict__ flag) {
  const int KN[5]   = {32768, 32768, 16384, 8192, 256};
  const int LGN[5]  = {8, 7, 7, 6, 2};
  const int KK[5]   = {128, 256, 128, 128, 64};
  const int OFF[5]  = {0, 32768, 65536, 81920, 90112};
  int l = blockIdx.y;
  int i = blockIdx.x * 256 + threadIdx.x;
  if (i >= KN[l]) return;
  int k = i >> LGN[l];
  int n = i & ((1 << LGN[l]) - 1);
  unsigned short v;
  if (*flag) v = ((const unsigned short*)wp.w[l])[i];
  else       v = f2bf(((const float*)wp.w[l])[i]);
  wt[OFF[l] + n * KK[l] + k] = v;
}

// ---- CSR build ----
__global__ void k_count(const int* __restrict__ dst, int* __restrict__ fill) {
  int e = blockIdx.x * 256 + threadIdx.x;
  if (e < NE) atomicAdd(&fill[dst[e]], 1);
}

__global__ void k_scan1(const int* __restrict__ deg, int* __restrict__ outp, int* __restrict__ csum) {
  __shared__ int s[256];
  int t = threadIdx.x, i = blockIdx.x * 256 + t;
  int v = (i < NN) ? deg[i] : 0;
  s[t] = v; __syncthreads();
  for (int o = 1; o < 256; o <<= 1) {
    int x = (t >= o) ? s[t - o] : 0; __syncthreads();
    s[t] += x; __syncthreads();
  }
  if (i < NN) outp[i] = s[t] - v;
  if (t == 255) csum[blockIdx.x] = s[255];
}

__global__ void k_scan2(int* __restrict__ csum, int nc) {
  __shared__ int s[256];
  int t = threadIdx.x;
  int v = (t < nc) ? csum[t] : 0;
  s[t] = v; __syncthreads();
  for (int o = 1; o < 256; o <<= 1) {
    int x = (t >= o) ? s[t - o] : 0; __syncthreads();
    s[t] += x; __syncthreads();
  }
  if (t < nc) csum[t] = s[t] - v;
}

__global__ void k_scan3(int* __restrict__ indptr, const int* __restrict__ csum, int* __restrict__ fill) {
  int i = blockIdx.x * 256 + threadIdx.x;
  if (i < NN) { int v = indptr[i] + csum[blockIdx.x]; indptr[i] = v; fill[i] = v; }
  if (i == NN) indptr[NN] = NE;
}

__global__ void k_fill(const int* __restrict__ src, const int* __restrict__ dst,
                       int* __restrict__ fill, int* __restrict__ csr) {
  int e = blockIdx.x * 256 + threadIdx.x;
  if (e < NE) { int p = atomicAdd(&fill[dst[e]], 1); csr[p] = src[e]; }
}

// ---- bf16 MFMA GEMM, no LDS: A frags direct from global, fused el/er ----
// BM=64 (4 waves x 16 rows), BN=64 (= one head's F), BK=32.
__global__ __launch_bounds__(256) void k_gemm_mfma(const unsigned short* __restrict__ A,
                                                   const unsigned short* __restrict__ Wt,
                                                   unsigned short* __restrict__ Zh,
                                                   const float* __restrict__ al,
                                                   const float* __restrict__ ar,
                                                   float* __restrict__ el, float* __restrict__ er,
                                                   int M, int K, int Nc, int H) {
  int tid = threadIdx.x;
  int w = tid >> 6, l = tid & 63;
  int l15 = l & 15, l16 = l >> 4;
  int row0 = blockIdx.y * 64, col0 = blockIdx.x * 64;
  int h = blockIdx.x;
  int arow = row0 + w * 16 + l15;
  if (arow >= M) arow = M - 1;  // clamp; OOB output rows are store-guarded
  const unsigned short* aptr = A + (size_t)arow * K + l16 * 8;
  f32x4 acc[4] = {};
#pragma unroll 4
  for (int k0 = 0; k0 < K; k0 += 32) {
    s16x8 afrag = *(const s16x8*)(aptr + k0);
#pragma unroll
    for (int nt = 0; nt < 4; nt++) {
      s16x8 bfrag = *(const s16x8*)&Wt[(size_t)(col0 + nt * 16 + l15) * K + k0 + l16 * 8];
      acc[nt] = __builtin_amdgcn_mfma_f32_16x16x32_bf16(afrag, bfrag, acc[nt], 0, 0, 0);
    }
  }
  // epilogue: Zh store + fused el/er
  float alv[4], arv[4];
#pragma unroll
  for (int nt = 0; nt < 4; nt++) {
    alv[nt] = al[h * 64 + nt * 16 + l15];
    arv[nt] = ar[h * 64 + nt * 16 + l15];
  }
#pragma unroll
  for (int r = 0; r < 4; r++) {
    int grow = row0 + w * 16 + l16 * 4 + r;
    bool ok = grow < M;
    float vl = 0.f, vr = 0.f;
#pragma unroll
    for (int nt = 0; nt < 4; nt++) {
      float a = acc[nt][r];
      if (ok) Zh[(size_t)grow * Nc + col0 + nt * 16 + l15] = f2bf(a);
      vl += a * alv[nt];
      vr += a * arv[nt];
    }
#pragma unroll
    for (int o = 1; o < 16; o <<= 1) {
      vl += __shfl_xor(vl, o, 64);
      vr += __shfl_xor(vr, o, 64);
    }
    if (l15 == 0 && ok) {
      el[grow * H + h] = vl;
      er[grow * H + h] = vr;
    }
  }
}

// ---- fused softmax + aggregation: wave per dst, single pass (no max-sub) ----
template <int HF, int H>
__global__ void k_agg_f(const int* __restrict__ indptr, const int* __restrict__ csr,
                        const float* __restrict__ el, const float* __restrict__ er,
                        const unsigned short* __restrict__ Zh, const float* __restrict__ bias,
                        unsigned short* __restrict__ outp) {
  const int LPE = HF / 8;   // lanes per edge
  const int EPI = 64 / LPE; // edges in flight
  int g = blockIdx.x * 256 + threadIdx.x;
  int n = g >> 6, lane = g & 63;
  if (n >= NN) return;
  int grp = lane / LPE;
  int fl = lane % LPE;
  int f0 = fl * 8;
  int h = f0 >> 6;
  int p0 = indptr[n], p1 = indptr[n + 1];
  float erv = er[n * H + h];
  float s = 0.f;
  float acc[8] = {};
#define AGG_BODY(P)                                                          \
  {                                                                          \
    int si_ = csr[P];                                                        \
    float e_ = el[si_ * H + h] + erv;                                        \
    e_ = (e_ > 0.f) ? e_ : 0.2f * e_;                                        \
    float x_ = __expf(fminf(e_, 80.f));                                      \
    s += x_;                                                                 \
    uint4 v_ = *(const uint4*)(Zh + (size_t)si_ * HF + f0);                  \
    unsigned int w_[4] = {v_.x, v_.y, v_.z, v_.w};                           \
    _Pragma("unroll") for (int q = 0; q < 4; q++) {                          \
      union { unsigned int u; float f; } lo_, hi_;                           \
      lo_.u = w_[q] << 16; hi_.u = w_[q] & 0xffff0000u;                      \
      acc[2 * q]     += x_ * lo_.f;                                          \
      acc[2 * q + 1] += x_ * hi_.f;                                          \
    }                                                                        \
  }
  int p = p0 + grp;
  for (; p + EPI < p1; p += 2 * EPI) { AGG_BODY(p); AGG_BODY(p + EPI); }
  if (p < p1) AGG_BODY(p);
#undef AGG_BODY
#pragma unroll
  for (int o = LPE; o < 64; o <<= 1) {
    s += __shfl_xor(s, o, 64);
#pragma unroll
    for (int i = 0; i < 8; i++) acc[i] += __shfl_xor(acc[i], o, 64);
  }
  if (grp == 0) {
    float inv = (p1 > p0) ? 1.f / s : 0.f;
    unsigned int pk[4];
#pragma unroll
    for (int q = 0; q < 4; q++) {
      float x0 = acc[2 * q] * inv + bias[f0 + 2 * q];
      float x1 = acc[2 * q + 1] * inv + bias[f0 + 2 * q + 1];
      x0 = (x0 > 0.f) ? x0 : expm1f(x0);
      x1 = (x1 > 0.f) ? x1 : expm1f(x1);
      pk[q] = (unsigned int)f2bf(x0) | ((unsigned int)f2bf(x1) << 16);
    }
    *(uint4*)&outp[(size_t)n * HF + f0] = make_uint4(pk[0], pk[1], pk[2], pk[3]);
  }
}

// ---- layer 5 linear (64 -> 4) + scores ----
__global__ void k_l5(const unsigned short* __restrict__ hb, const float* __restrict__ W5,
                     const float* __restrict__ al5, const float* __restrict__ ar5,
                     float* __restrict__ z5, float* __restrict__ el, float* __restrict__ er) {
  __shared__ float W5s[256];
  int t = threadIdx.x;
  W5s[t] = W5[t];
  __syncthreads();
  int n = blockIdx.x * 256 + t;
  if (n >= NN) return;
  float z[4] = {};
#pragma unroll
  for (int kq = 0; kq < 8; kq++) {
    uint4 v = *(const uint4*)&hb[(size_t)n * 64 + kq * 8];
    unsigned int w_[4] = {v.x, v.y, v.z, v.w};
#pragma unroll
    for (int q = 0; q < 4; q++) {
      union { unsigned int u; float f; } lo, hi;
      lo.u = w_[q] << 16; hi.u = w_[q] & 0xffff0000u;
      int k = kq * 8 + 2 * q;
#pragma unroll
      for (int c = 0; c < 4; c++) z[c] += lo.f * W5s[k * 4 + c] + hi.f * W5s[(k + 1) * 4 + c];
    }
  }
  el[n] = z[0] * al5[0] + z[1] * al5[1] + z[2] * al5[2] + z[3] * al5[3];
  er[n] = z[0] * ar5[0] + z[1] * ar5[1] + z[2] * ar5[2] + z[3] * ar5[3];
  *(float4*)&z5[n * 4] = make_float4(z[0], z[1], z[2], z[3]);
}

// ---- final fused softmax+agg (H=1,F=4), thread per dst ----
__global__ void k_agg4_f(const int* __restrict__ indptr, const int* __restrict__ csr,
                         const float* __restrict__ el, const float* __restrict__ er,
                         const float* __restrict__ Z, const float* __restrict__ bias,
                         void* __restrict__ outp, const int* __restrict__ flag) {
  int n = blockIdx.x * 256 + threadIdx.x;
  if (n >= NN) return;
  int p0 = indptr[n], p1 = indptr[n + 1];
  float erv = er[n];
  float s = 0.f;
  float ax = 0.f, ay = 0.f, az = 0.f, aw = 0.f;
  for (int p = p0; p < p1; p++) {
    int si = csr[p];
    float e = el[si] + erv;
    e = (e > 0.f) ? e : 0.2f * e;
    float x = __expf(fminf(e, 80.f));
    s += x;
    float4 z = *(const float4*)&Z[si * 4];
    ax += x * z.x; ay += x * z.y; az += x * z.z; aw += x * z.w;
  }
  float inv = (p1 > p0) ? 1.f / s : 0.f;
  ax = ax * inv + bias[0]; ay = ay * inv + bias[1];
  az = az * inv + bias[2]; aw = aw * inv + bias[3];
  if (*flag) {
    unsigned short* o = (unsigned short*)outp;
    o[n * 4 + 0] = f2bf(ax); o[n * 4 + 1] = f2bf(ay);
    o[n * 4 + 2] = f2bf(az); o[n * 4 + 3] = f2bf(aw);
  } else {
    float* o = (float*)outp;
    o[n * 4 + 0] = ax; o[n * 4 + 1] = ay; o[n * 4 + 2] = az; o[n * 4 + 3] = aw;
  }
}

extern "C" void kernel_launch(void* const* d_in, const int* in_sizes, int n_in,
                              void* d_out, int out_size, void* d_ws, size_t ws_size,
                              hipStream_t stream) {
  (void)in_sizes; (void)n_in; (void)out_size; (void)ws_size;
  static const int fin[5] = {128, 256, 128, 128, 64};
  static const int Hh[5]  = {4, 2, 2, 1, 1};
  static const int HF[5]  = {256, 128, 128, 64, 4};
  static const int WtOff[5] = {0, 32768, 65536, 81920, 90112};

  char* ws = (char*)d_ws;
  size_t cur = 0;
  auto alloc = [&](size_t b) -> void* { void* p = ws + cur; cur += (b + 255) & ~(size_t)255; return p; };

  int*   flag   = (int*)alloc(4);
  int*   csum   = (int*)alloc(1024);
  int*   indptr = (int*)alloc((NN + 1) * 4);
  int*   fill   = (int*)alloc((size_t)NN * 4);
  int*   csr    = (int*)alloc((size_t)NE * 4);
  float* el     = (float*)alloc((size_t)NN * 4 * 4);
  float* er     = (float*)alloc((size_t)NN * 4 * 4);
  float* smallf = (float*)alloc(100000 * 4);
  unsigned short* xh   = (unsigned short*)alloc((size_t)NN * 128 * 2);
  unsigned short* wt   = (unsigned short*)alloc(90368 * 2);
  unsigned short* hb0  = (unsigned short*)alloc((size_t)NN * 256 * 2);
  unsigned short* hb1  = (unsigned short*)alloc((size_t)NN * 256 * 2);
  unsigned short* zh   = (unsigned short*)alloc((size_t)NN * 256 * 2);
  float* z5     = (float*)alloc((size_t)NN * 4 * 4);

  const int* srcIdx = (const int*)d_in[1];
  const int* dstIdx = (const int*)d_in[2];

  SmallPack pk;
  WPack wpk;
  int off = 0;
  int aloff[5], aroff[5], boff[5], w5off = 0;
  for (int i = 0; i < 5; i++) {
    pk.src[i * 4 + 0] = d_in[3 + i * 4 + 0]; pk.off[i * 4 + 0] = off;
    wpk.w[i] = d_in[3 + i * 4 + 0];
    if (i == 4) w5off = off;
    off += fin[i] * HF[i];
    pk.src[i * 4 + 1] = d_in[3 + i * 4 + 1]; pk.off[i * 4 + 1] = off; aloff[i] = off; off += HF[i];
    pk.src[i * 4 + 2] = d_in[3 + i * 4 + 2]; pk.off[i * 4 + 2] = off; aroff[i] = off; off += HF[i];
    pk.src[i * 4 + 3] = d_in[3 + i * 4 + 3]; pk.off[i * 4 + 3] = off; boff[i]  = off; off += HF[i];
  }
  pk.off[20] = off;
  int totalSmall = off;

  k_detect<<<1, 64, 0, stream>>>((const unsigned short*)d_in[0], flag);
  hipMemsetAsync(fill, 0, (size_t)NN * 4, stream);
  { int n = NN * 128; k_cvt_x<<<(n + 255) / 256, 256, 0, stream>>>(d_in[0], xh, n, flag); }
  k_cvt_small<<<(totalSmall + 255) / 256, 256, 0, stream>>>(pk, smallf, totalSmall, flag);
  { dim3 g(128, 5); k_prep_w<<<g, 256, 0, stream>>>(wpk, wt, flag); }
  k_count<<<(NE + 255) / 256, 256, 0, stream>>>(dstIdx, fill);
  int nch = (NN + 255) / 256;
  k_scan1<<<nch, 256, 0, stream>>>(fill, indptr, csum);
  k_scan2<<<1, 256, 0, stream>>>(csum, nch);
  k_scan3<<<nch, 256, 0, stream>>>(indptr, csum, fill);
  k_fill<<<(NE + 255) / 256, 256, 0, stream>>>(srcIdx, dstIdx, fill, csr);

  const int nwaveblk = (NN * 64 + 255) / 256;

  const unsigned short* hin = xh;
  unsigned short* hout = hb0;
  for (int L = 0; L < 4; L++) {
    int K = fin[L], Nc = HF[L], H = Hh[L];
    const float* alp = smallf + aloff[L];
    const float* arp = smallf + aroff[L];
    const float* bp  = smallf + boff[L];
    dim3 gg(Nc / 64, (NN + 63) / 64);
    k_gemm_mfma<<<gg, 256, 0, stream>>>(hin, wt + WtOff[L], zh, alp, arp, el, er, NN, K, Nc, H);
    if (L == 0)      k_agg_f<256, 4><<<nwaveblk, 256, 0, stream>>>(indptr, csr, el, er, zh, bp, hout);
    else if (L == 3) k_agg_f<64, 1><<<nwaveblk, 256, 0, stream>>>(indptr, csr, el, er, zh, bp, hout);
    else             k_agg_f<128, 2><<<nwaveblk, 256, 0, stream>>>(indptr, csr, el, er, zh, bp, hout);
    hin = hout;
    hout = (hout == hb0) ? hb1 : hb0;
  }
  // layer 5
  k_l5<<<(NN + 255) / 256, 256, 0, stream>>>(hin, smallf + w5off, smallf + aloff[4],
                                             smallf + aroff[4], z5, el, er);
  k_agg4_f<<<(NN + 255) / 256, 256, 0, stream>>>(indptr, csr, el, er, z5, smallf + boff[4], d_out, flag);
}